// Round 2
// baseline (680.036 us; speedup 1.0000x reference)
//
#include <hip/hip_runtime.h>
#include <stdint.h>

typedef unsigned int u32;
typedef unsigned short u16;
typedef __attribute__((ext_vector_type(4))) float f32x4;
typedef __attribute__((ext_vector_type(8))) short s16x8;

#define DEV static __device__ __forceinline__

DEV u16 f2bf(float x){
  u32 u = __builtin_bit_cast(u32, x);
  u32 r = u + 0x7FFFu + ((u >> 16) & 1u);
  return (u16)(r >> 16);
}
DEV float bf2f(u16 b){ return __builtin_bit_cast(float, (u32)b << 16); }
DEV u32 pack2(float a, float b){ return ((u32)f2bf(b) << 16) | (u32)f2bf(a); }

DEV void gload_lds16(const void* g, void* l){
  __builtin_amdgcn_global_load_lds(
      (const __attribute__((address_space(1))) void*)g,
      (__attribute__((address_space(3))) void*)l,
      16, 0, 0);
}

// ---------------- weight f32 -> bf16 ----------------
__global__ void cvt_bf16_k(const float* __restrict__ in, u16* __restrict__ out, int n){
  int i = (blockIdx.x * blockDim.x + threadIdx.x) * 4;
  int stride = gridDim.x * blockDim.x * 4;
  for(; i < n; i += stride){
    float4 v = *(const float4*)(in + i);
    u32 lo = pack2(v.x, v.y), hi = pack2(v.z, v.w);
    *(uint2*)(out + i) = make_uint2(lo, hi);
  }
}

// ---------------- LN over rows of 512, f32 in -> bf16 out ----------------
__global__ __launch_bounds__(64) void ln_rows_k(const float* __restrict__ in,
    const float* __restrict__ gw, const float* __restrict__ bw, u16* __restrict__ out){
  const int row = blockIdx.x, lane = threadIdx.x;
  const float* p = in + (size_t)row * 512 + lane * 8;
  float4 a = *(const float4*)p;
  float4 b = *(const float4*)(p + 4);
  float x[8] = {a.x,a.y,a.z,a.w,b.x,b.y,b.z,b.w};
  float s = 0.f, q = 0.f;
  #pragma unroll
  for(int e = 0; e < 8; e++){ s += x[e]; q += x[e]*x[e]; }
  #pragma unroll
  for(int m = 1; m < 64; m <<= 1){ s += __shfl_xor(s, m); q += __shfl_xor(q, m); }
  float mean = s * (1.f/512.f);
  float rs = rsqrtf(q * (1.f/512.f) - mean*mean + 1e-5f);
  const float* gp = gw + lane*8; const float* bp = bw + lane*8;
  float4 g0 = *(const float4*)gp, g1 = *(const float4*)(gp+4);
  float4 b0 = *(const float4*)bp, b1 = *(const float4*)(bp+4);
  float gg[8] = {g0.x,g0.y,g0.z,g0.w,g1.x,g1.y,g1.z,g1.w};
  float bb[8] = {b0.x,b0.y,b0.z,b0.w,b1.x,b1.y,b1.z,b1.w};
  float y[8];
  #pragma unroll
  for(int e = 0; e < 8; e++) y[e] = (x[e]-mean)*rs*gg[e] + bb[e];
  uint4 ov = { pack2(y[0],y[1]), pack2(y[2],y[3]), pack2(y[4],y[5]), pack2(y[6],y[7]) };
  *(uint4*)(out + (size_t)row*512 + lane*8) = ov;
}

// ---------------- double LN of latents (norm_latents then pa.norm_latents) ----------------
__global__ __launch_bounds__(64) void lat_ln2_k(const float* __restrict__ lp,
    const float* __restrict__ g1, const float* __restrict__ b1,
    const float* __restrict__ g2, const float* __restrict__ b2, u16* __restrict__ out){
  const int row = blockIdx.x, lane = threadIdx.x;
  const float* p = lp + (size_t)row*512 + lane*8;
  float4 a = *(const float4*)p;
  float4 b4 = *(const float4*)(p + 4);
  float x[8] = {a.x,a.y,a.z,a.w,b4.x,b4.y,b4.z,b4.w};
  float s = 0.f, q = 0.f;
  #pragma unroll
  for(int e = 0; e < 8; e++){ s += x[e]; q += x[e]*x[e]; }
  #pragma unroll
  for(int m = 1; m < 64; m <<= 1){ s += __shfl_xor(s, m); q += __shfl_xor(q, m); }
  float mean = s*(1.f/512.f);
  float rs = rsqrtf(q*(1.f/512.f) - mean*mean + 1e-5f);
  float t[8];
  #pragma unroll
  for(int e = 0; e < 8; e++) t[e] = (x[e]-mean)*rs*g1[lane*8+e] + b1[lane*8+e];
  float s2 = 0.f, q2 = 0.f;
  #pragma unroll
  for(int e = 0; e < 8; e++){ s2 += t[e]; q2 += t[e]*t[e]; }
  #pragma unroll
  for(int m = 1; m < 64; m <<= 1){ s2 += __shfl_xor(s2, m); q2 += __shfl_xor(q2, m); }
  float mean2 = s2*(1.f/512.f);
  float rs2 = rsqrtf(q2*(1.f/512.f) - mean2*mean2 + 1e-5f);
  float y[8];
  #pragma unroll
  for(int e = 0; e < 8; e++) y[e] = (t[e]-mean2)*rs2*g2[lane*8+e] + b2[lane*8+e];
  uint4 ov = { pack2(y[0],y[1]), pack2(y[2],y[3]), pack2(y[4],y[5]), pack2(y[6],y[7]) };
  *(uint4*)(out + (size_t)row*512 + lane*8) = ov;
}

// ---------------- generic bf16 MFMA GEMM: C = epi(A @ B^T + bias) ----------------
// A [M,K] bf16 row-major, B [N,K] bf16 row-major (weights), all dims %128/%64.
// EPI bits: 1 = store bf16 (else f32), 2 = quick-gelu, 4 = add resid (f32)
template<int EPI>
__global__ __launch_bounds__(256) void gemm_bt_k(
    const u16* __restrict__ A, const u16* __restrict__ B,
    const float* __restrict__ bias, const float* __restrict__ resid,
    float* __restrict__ outF, u16* __restrict__ outB,
    int M, int N, int K, float scale)
{
  __shared__ __align__(16) u16 As[128*64];
  __shared__ __align__(16) u16 Bs[128*64];
  const int tid = threadIdx.x;
  const int lane = tid & 63, w = tid >> 6;
  const int m0 = blockIdx.y * 128, n0 = blockIdx.x * 128;
  const int wm = (w >> 1) * 64, wn = (w & 1) * 64;
  const int g = lane >> 4, q = lane & 15;
  f32x4 acc[4][4] = {};

  const int srow = w*32 + (lane >> 3);
  const int scol = (lane & 7) * 8;
  const u16* Abase = A + (size_t)(m0 + srow) * K + scol;
  const u16* Bbase = B + (size_t)(n0 + srow) * K + scol;

  for(int kt = 0; kt < K; kt += 64){
    #pragma unroll
    for(int c = 0; c < 4; c++){
      gload_lds16(Abase + (size_t)c*8*K + kt, &As[(w*32 + c*8) * 64]);
      gload_lds16(Bbase + (size_t)c*8*K + kt, &Bs[(w*32 + c*8) * 64]);
    }
    __syncthreads();
    #pragma unroll
    for(int kk = 0; kk < 2; kk++){
      s16x8 af[4], bf[4];
      #pragma unroll
      for(int mi = 0; mi < 4; mi++) af[mi] = *(const s16x8*)&As[(wm + mi*16 + q)*64 + kk*32 + g*8];
      #pragma unroll
      for(int ni = 0; ni < 4; ni++) bf[ni] = *(const s16x8*)&Bs[(wn + ni*16 + q)*64 + kk*32 + g*8];
      #pragma unroll
      for(int mi = 0; mi < 4; mi++)
        #pragma unroll
        for(int ni = 0; ni < 4; ni++)
          acc[mi][ni] = __builtin_amdgcn_mfma_f32_16x16x32_bf16(af[mi], bf[ni], acc[mi][ni], 0, 0, 0);
    }
    __syncthreads();
  }
  #pragma unroll
  for(int ni = 0; ni < 4; ni++){
    const int colg = n0 + wn + ni*16 + q;
    const float bia = bias[colg];
    #pragma unroll
    for(int mi = 0; mi < 4; mi++){
      #pragma unroll
      for(int r = 0; r < 4; r++){
        const int rowg = m0 + wm + mi*16 + g*4 + r;
        float v = (acc[mi][ni][r] + bia) * scale;
        if(EPI & 2){ v = v / (1.f + __expf(-1.702f * v)); }
        if(EPI & 4){ v += resid[(size_t)rowg * N + colg]; }
        if(EPI & 1){ outB[(size_t)rowg * N + colg] = f2bf(v); }
        else       { outF[(size_t)rowg * N + colg] = v; }
      }
    }
  }
}

// ---------------- perceiver flash attention ----------------
// q [128,1024] bf16 (pre-scaled), kvx [8,4096,2048], kvl [128,2048], o [1024,1024] bf16
DEV void stage_write_kv(u16* Ks, u16* VTs, int sj, int sd, uint4 kreg, uint4 vreg){
  *(uint4*)((char*)Ks + sj*256 + ((sd*16) ^ ((sj & 7) << 4))) = kreg;
  const u16* vp = (const u16*)&vreg;
  #pragma unroll
  for(int e = 0; e < 8; e++){
    int dd = sd*8 + e;
    *((u16*)((char*)VTs + dd*64 + ((sj*2) ^ ((dd & 3) << 4)))) = vp[e];
  }
}

__global__ __launch_bounds__(512) void attn_pa_k(
    const u16* __restrict__ qb, const u16* __restrict__ kvx,
    const u16* __restrict__ kvl, u16* __restrict__ o)
{
  const int h = blockIdx.x, b = blockIdx.y;
  const int tid = threadIdx.x;
  const int lane = tid & 63, w = tid >> 6;
  const int g = lane >> 4, q = lane & 15;
  __shared__ __align__(16) u16 Ks[32*128];   // [j][d] xor-swizzled
  __shared__ __align__(16) u16 VTs[128*32];  // [d][j] xor-swizzled

  s16x8 qf[4];
  const int q0 = w * 16;
  #pragma unroll
  for(int kk = 0; kk < 4; kk++)
    qf[kk] = *(const s16x8*)&qb[(size_t)(q0 + q)*1024 + h*128 + kk*32 + g*8];

  f32x4 oa[8] = {};
  float mrun = -1e30f, lsum = 0.f;

  const int sj = tid >> 4, sd = tid & 15;
  const int hk = h*128 + sd*8;

  uint4 kreg, vreg;
  {
    const u16* p = kvx + ((size_t)b*4096 + sj) * 2048;
    kreg = *(const uint4*)(p + hk);
    vreg = *(const uint4*)(p + 1024 + hk);
  }
  stage_write_kv(Ks, VTs, sj, sd, kreg, vreg);

  const int NC = 132;  // 4224 / 32
  for(int c = 0; c < NC; c++){
    __syncthreads();
    uint4 kn, vn;
    if(c + 1 < NC){
      int jr = (c+1)*32 + sj;
      const u16* p = (jr < 4096) ? (kvx + ((size_t)b*4096 + jr)*2048)
                                 : (kvl + (size_t)(jr - 4096)*2048);
      kn = *(const uint4*)(p + hk);
      vn = *(const uint4*)(p + 1024 + hk);
    }
    // sim^T = mfma(K, Q): C[j][q], col=q=lane&15, row j = jt*16 + g*4 + r
    f32x4 s0 = {}, s1 = {};
    #pragma unroll
    for(int kk = 0; kk < 4; kk++){
      const int r0 = q, r1 = 16 + q;
      s16x8 kf0 = *(const s16x8*)((const char*)Ks + r0*256 + ((kk*64 + g*16) ^ ((r0 & 7) << 4)));
      s16x8 kf1 = *(const s16x8*)((const char*)Ks + r1*256 + ((kk*64 + g*16) ^ ((r1 & 7) << 4)));
      s0 = __builtin_amdgcn_mfma_f32_16x16x32_bf16(kf0, qf[kk], s0, 0, 0, 0);
      s1 = __builtin_amdgcn_mfma_f32_16x16x32_bf16(kf1, qf[kk], s1, 0, 0, 0);
    }
    float cmax = fmaxf(fmaxf(fmaxf(s0[0], s0[1]), fmaxf(s0[2], s0[3])),
                       fmaxf(fmaxf(s1[0], s1[1]), fmaxf(s1[2], s1[3])));
    cmax = fmaxf(cmax, __shfl_xor(cmax, 16));
    cmax = fmaxf(cmax, __shfl_xor(cmax, 32));
    if(!__all(cmax <= mrun)){
      float nm = fmaxf(mrun, cmax);
      float sc = __expf(mrun - nm);
      #pragma unroll
      for(int dt = 0; dt < 8; dt++){
        oa[dt][0] *= sc; oa[dt][1] *= sc; oa[dt][2] *= sc; oa[dt][3] *= sc;
      }
      lsum *= sc; mrun = nm;
    }
    float p0 = __expf(s0[0]-mrun), p1 = __expf(s0[1]-mrun), p2 = __expf(s0[2]-mrun), p3 = __expf(s0[3]-mrun);
    float p4 = __expf(s1[0]-mrun), p5 = __expf(s1[1]-mrun), p6 = __expf(s1[2]-mrun), p7 = __expf(s1[3]-mrun);
    float cs = ((p0+p1)+(p2+p3)) + ((p4+p5)+(p6+p7));
    cs += __shfl_xor(cs, 16); cs += __shfl_xor(cs, 32);
    lsum += cs;
    // redistribute P^T (col=q, row=j) into PV B-fragment (lane needs j = g*8..g*8+7 for its q)
    u32 t0a = pack2(p0,p1), t0b = pack2(p2,p3), t1a = pack2(p4,p5), t1b = pack2(p6,p7);
    int srcA = ((g & 1) * 2) * 16 + q;
    int srcB = srcA + 16;
    u32 a0 = (u32)__shfl((int)t0a, srcA), b0 = (u32)__shfl((int)t1a, srcA);
    u32 a1 = (u32)__shfl((int)t0b, srcA), b1 = (u32)__shfl((int)t1b, srcA);
    u32 a2 = (u32)__shfl((int)t0a, srcB), b2 = (u32)__shfl((int)t1a, srcB);
    u32 a3 = (u32)__shfl((int)t0b, srcB), b3 = (u32)__shfl((int)t1b, srcB);
    bool lo = (lane < 32);
    uint4 pu;
    pu.x = lo ? a0 : b0; pu.y = lo ? a1 : b1; pu.z = lo ? a2 : b2; pu.w = lo ? a3 : b3;
    s16x8 pf = __builtin_bit_cast(s16x8, pu);
    // o^T[d][q] += mfma(V^T, P)
    #pragma unroll
    for(int dt = 0; dt < 8; dt++){
      const int dr = dt*16 + q;
      s16x8 vf = *(const s16x8*)((const char*)VTs + dr*64 + ((g*16) ^ ((dr & 3) << 4)));
      oa[dt] = __builtin_amdgcn_mfma_f32_16x16x32_bf16(vf, pf, oa[dt], 0, 0, 0);
    }
    __syncthreads();
    if(c + 1 < NC){ kreg = kn; vreg = vn; stage_write_kv(Ks, VTs, sj, sd, kreg, vreg); }
  }
  float inv = 1.f / lsum;
  #pragma unroll
  for(int dt = 0; dt < 8; dt++){
    #pragma unroll
    for(int r = 0; r < 4; r++){
      int dd = dt*16 + g*4 + r;
      o[(size_t)(b*128 + q0 + q)*1024 + h*128 + dd] = f2bf(oa[dt][r] * inv);
    }
  }
}

// ---------------- MHA over batch axis (i,j = 8) ----------------
__global__ __launch_bounds__(64) void attn2_k(const float* __restrict__ qkv2, u16* __restrict__ o2){
  const int n = blockIdx.x, h = blockIdx.y;
  const int lane = threadIdx.x;
  __shared__ float qs[8][64], ks[8][64], vs[8][64], as_[8][8];
  #pragma unroll
  for(int i = 0; i < 8; i++){
    size_t base = (size_t)(i*128 + n) * 1536 + h*64 + lane;
    qs[i][lane] = qkv2[base] * 0.125f;
    ks[i][lane] = qkv2[base + 512];
    vs[i][lane] = qkv2[base + 1024];
  }
  __syncthreads();
  const int i = lane >> 3, j = lane & 7;
  float s = 0.f;
  #pragma unroll
  for(int d = 0; d < 64; d++) s += qs[i][d] * ks[j][d];
  float mx = s;
  mx = fmaxf(mx, __shfl_xor(mx, 1)); mx = fmaxf(mx, __shfl_xor(mx, 2)); mx = fmaxf(mx, __shfl_xor(mx, 4));
  float p = __expf(s - mx);
  float ps = p;
  ps += __shfl_xor(ps, 1); ps += __shfl_xor(ps, 2); ps += __shfl_xor(ps, 4);
  as_[i][j] = p / ps;
  __syncthreads();
  const int d0 = (lane & 7) * 8, i2 = lane >> 3;
  #pragma unroll
  for(int dd = 0; dd < 8; dd++){
    float acc = 0.f;
    #pragma unroll
    for(int jj = 0; jj < 8; jj++) acc += as_[i2][jj] * vs[jj][d0 + dd];
    o2[(size_t)(i2*128 + n) * 512 + h*64 + d0 + dd] = f2bf(acc);
  }
}

extern "C" void kernel_launch(void* const* d_in, const int* in_sizes, int n_in,
                              void* d_out, int out_size, void* d_ws, size_t ws_size,
                              hipStream_t stream){
  const float* visual  = (const float*)d_in[0];
  const float* latents = (const float*)d_in[1];
  const float* nl_g    = (const float*)d_in[2];
  const float* nl_b    = (const float*)d_in[3];
  const float* pa_nm_g = (const float*)d_in[4];
  const float* pa_nm_b = (const float*)d_in[5];
  const float* pa_nl_g = (const float*)d_in[6];
  const float* pa_nl_b = (const float*)d_in[7];
  const float* Wq  = (const float*)d_in[8];
  const float* bq  = (const float*)d_in[9];
  const float* Wkv = (const float*)d_in[10];
  const float* bkv = (const float*)d_in[11];
  const float* Wo  = (const float*)d_in[12];
  const float* bo  = (const float*)d_in[13];
  const float* Wip = (const float*)d_in[14];
  const float* bip = (const float*)d_in[15];
  const float* Wop = (const float*)d_in[16];
  const float* bop = (const float*)d_in[17];
  const float* ln1_g = (const float*)d_in[18];
  const float* ln1_b = (const float*)d_in[19];
  const float* ln2_g = (const float*)d_in[20];
  const float* ln2_b = (const float*)d_in[21];
  const float* Wfc = (const float*)d_in[22];
  const float* bfc = (const float*)d_in[23];
  const float* Wpj = (const float*)d_in[24];
  const float* bpj = (const float*)d_in[25];
  float* out = (float*)d_out;

  char* p = (char*)d_ws;
  auto alloc = [&](size_t n)->char*{ char* r = p; p += (n + 255) & ~(size_t)255; return r; };
  u16* Wq_b  = (u16*)alloc((size_t)1024*512*2);
  u16* Wkv_b = (u16*)alloc((size_t)2048*512*2);
  u16* Wo_b  = (u16*)alloc((size_t)512*1024*2);
  u16* Wip_b = (u16*)alloc((size_t)1536*512*2);
  u16* Wop_b = (u16*)alloc((size_t)512*512*2);
  u16* Wfc_b = (u16*)alloc((size_t)2048*512*2);
  u16* Wpj_b = (u16*)alloc((size_t)512*2048*2);
  u16* l_b   = (u16*)alloc((size_t)128*512*2);
  u16* q_b   = (u16*)alloc((size_t)128*1024*2);
  u16* kvl_b = (u16*)alloc((size_t)128*2048*2);
  u16* xln_b = (u16*)alloc((size_t)32768*512*2);
  u16* kvx_b = (u16*)alloc((size_t)32768*2048*2);
  u16* opa_b = (u16*)alloc((size_t)1024*1024*2);
  float* lat1 = (float*)alloc((size_t)1024*512*4);
  u16* y_b   = (u16*)alloc((size_t)1024*512*2);
  float* qkv2 = (float*)alloc((size_t)1024*1536*4);
  u16* o2_b  = (u16*)alloc((size_t)1024*512*2);
  float* lat2 = (float*)alloc((size_t)1024*512*4);
  u16* z_b   = (u16*)alloc((size_t)1024*512*2);
  u16* h1_b  = (u16*)alloc((size_t)1024*2048*2);

  auto cvt = [&](const float* src, u16* dst, int n){
    int blocks = (n/4 + 255) / 256; if(blocks > 1024) blocks = 1024;
    cvt_bf16_k<<<blocks, 256, 0, stream>>>(src, dst, n);
  };
  cvt(Wq,  Wq_b,  1024*512);
  cvt(Wkv, Wkv_b, 2048*512);
  cvt(Wo,  Wo_b,  512*1024);
  cvt(Wip, Wip_b, 1536*512);
  cvt(Wop, Wop_b, 512*512);
  cvt(Wfc, Wfc_b, 2048*512);
  cvt(Wpj, Wpj_b, 512*2048);

  lat_ln2_k<<<128, 64, 0, stream>>>(latents, nl_g, nl_b, pa_nl_g, pa_nl_b, l_b);
  ln_rows_k<<<32768, 64, 0, stream>>>(visual, pa_nm_g, pa_nm_b, xln_b);

  // q = (l @ Wq^T + bq) * dh^-0.5   -> bf16 [128,1024]
  gemm_bt_k<1><<<dim3(8, 1), 256, 0, stream>>>(l_b, Wq_b, bq, nullptr, nullptr, q_b,
                                               128, 1024, 512, 0.08838834764831845f);
  // kv_l = l @ Wkv^T + bkv          -> bf16 [128,2048]
  gemm_bt_k<1><<<dim3(16, 1), 256, 0, stream>>>(l_b, Wkv_b, bkv, nullptr, nullptr, kvl_b,
                                                128, 2048, 512, 1.f);
  // kv_x = ln(visual) @ Wkv^T + bkv -> bf16 [32768,2048]
  gemm_bt_k<1><<<dim3(16, 256), 256, 0, stream>>>(xln_b, Wkv_b, bkv, nullptr, nullptr, kvx_b,
                                                  32768, 2048, 512, 1.f);
  attn_pa_k<<<dim3(8, 8), 512, 0, stream>>>(q_b, kvx_b, kvl_b, opa_b);
  // lat1 = o @ Wo^T + bo -> f32 [1024,512]
  gemm_bt_k<0><<<dim3(4, 8), 256, 0, stream>>>(opa_b, Wo_b, bo, nullptr, lat1, nullptr,
                                               1024, 512, 1024, 1.f);
  ln_rows_k<<<1024, 64, 0, stream>>>(lat1, ln1_g, ln1_b, y_b);
  // qkv2 = y @ in_proj^T + b -> f32 [1024,1536]
  gemm_bt_k<0><<<dim3(12, 8), 256, 0, stream>>>(y_b, Wip_b, bip, nullptr, qkv2, nullptr,
                                                1024, 1536, 512, 1.f);
  attn2_k<<<dim3(128, 8), 64, 0, stream>>>(qkv2, o2_b);
  // lat2 = lat1 + o2 @ out_proj^T + b -> f32
  gemm_bt_k<4><<<dim3(4, 8), 256, 0, stream>>>(o2_b, Wop_b, bop, lat1, lat2, nullptr,
                                               1024, 512, 512, 1.f);
  ln_rows_k<<<1024, 64, 0, stream>>>(lat2, ln2_g, ln2_b, z_b);
  // h1 = qgelu(z @ Wfc^T + bfc) -> bf16 [1024,2048]
  gemm_bt_k<3><<<dim3(16, 8), 256, 0, stream>>>(z_b, Wfc_b, bfc, nullptr, nullptr, h1_b,
                                                1024, 2048, 512, 1.f);
  // out = lat2 + h1 @ Wproj^T + bproj -> f32 [1024,512]
  gemm_bt_k<4><<<dim3(4, 8), 256, 0, stream>>>(h1_b, Wpj_b, bpj, lat2, out, nullptr,
                                               1024, 512, 2048, 1.f);
}

// Round 10
// 419.254 us; speedup vs baseline: 1.6220x; 1.6220x over previous
//
#include <hip/hip_runtime.h>
#include <stdint.h>

typedef unsigned int u32;
typedef unsigned short u16;
typedef __attribute__((ext_vector_type(4))) float f32x4;
typedef __attribute__((ext_vector_type(8))) short s16x8;

#define DEV static __device__ __forceinline__

DEV u16 f2bf(float x){
  u32 u = __builtin_bit_cast(u32, x);
  u32 r = u + 0x7FFFu + ((u >> 16) & 1u);
  return (u16)(r >> 16);
}
DEV float bf2f(u16 b){ return __builtin_bit_cast(float, (u32)b << 16); }
DEV u32 pack2(float a, float b){ return ((u32)f2bf(b) << 16) | (u32)f2bf(a); }

DEV void gload_lds16(const void* g, void* l){
  __builtin_amdgcn_global_load_lds(
      (const __attribute__((address_space(1))) void*)g,
      (__attribute__((address_space(3))) void*)l,
      16, 0, 0);
}

// ---------------- fused weight f32 -> bf16 (7 segments, 1 launch) ----------------
struct CvtArgs { const float* src[7]; u16* dst[7]; int n[7]; };
__global__ void cvt_all_k(CvtArgs a){
  const int seg = blockIdx.y;
  const int n = a.n[seg];
  const float* __restrict__ in = a.src[seg];
  u16* __restrict__ out = a.dst[seg];
  int i = (blockIdx.x * blockDim.x + threadIdx.x) * 4;
  const int stride = gridDim.x * blockDim.x * 4;
  for(; i < n; i += stride){
    float4 v = *(const float4*)(in + i);
    u32 lo = pack2(v.x, v.y), hi = pack2(v.z, v.w);
    *(uint2*)(out + i) = make_uint2(lo, hi);
  }
}

// ---------------- LN over rows of 512, f32 in -> bf16 out ----------------
__global__ __launch_bounds__(64) void ln_rows_k(const float* __restrict__ in,
    const float* __restrict__ gw, const float* __restrict__ bw, u16* __restrict__ out){
  const int row = blockIdx.x, lane = threadIdx.x;
  const float* p = in + (size_t)row * 512 + lane * 8;
  float4 a = *(const float4*)p;
  float4 b = *(const float4*)(p + 4);
  float x[8] = {a.x,a.y,a.z,a.w,b.x,b.y,b.z,b.w};
  float s = 0.f, q = 0.f;
  #pragma unroll
  for(int e = 0; e < 8; e++){ s += x[e]; q += x[e]*x[e]; }
  #pragma unroll
  for(int m = 1; m < 64; m <<= 1){ s += __shfl_xor(s, m); q += __shfl_xor(q, m); }
  float mean = s * (1.f/512.f);
  float rs = rsqrtf(q * (1.f/512.f) - mean*mean + 1e-5f);
  const float* gp = gw + lane*8; const float* bp = bw + lane*8;
  float4 g0 = *(const float4*)gp, g1 = *(const float4*)(gp+4);
  float4 b0 = *(const float4*)bp, b1 = *(const float4*)(bp+4);
  float gg[8] = {g0.x,g0.y,g0.z,g0.w,g1.x,g1.y,g1.z,g1.w};
  float bb[8] = {b0.x,b0.y,b0.z,b0.w,b1.x,b1.y,b1.z,b1.w};
  float y[8];
  #pragma unroll
  for(int e = 0; e < 8; e++) y[e] = (x[e]-mean)*rs*gg[e] + bb[e];
  uint4 ov = { pack2(y[0],y[1]), pack2(y[2],y[3]), pack2(y[4],y[5]), pack2(y[6],y[7]) };
  *(uint4*)(out + (size_t)row*512 + lane*8) = ov;
}

// ---------------- double LN of latents ----------------
__global__ __launch_bounds__(64) void lat_ln2_k(const float* __restrict__ lp,
    const float* __restrict__ g1, const float* __restrict__ b1,
    const float* __restrict__ g2, const float* __restrict__ b2, u16* __restrict__ out){
  const int row = blockIdx.x, lane = threadIdx.x;
  const float* p = lp + (size_t)row*512 + lane*8;
  float4 a = *(const float4*)p;
  float4 b4 = *(const float4*)(p + 4);
  float x[8] = {a.x,a.y,a.z,a.w,b4.x,b4.y,b4.z,b4.w};
  float s = 0.f, q = 0.f;
  #pragma unroll
  for(int e = 0; e < 8; e++){ s += x[e]; q += x[e]*x[e]; }
  #pragma unroll
  for(int m = 1; m < 64; m <<= 1){ s += __shfl_xor(s, m); q += __shfl_xor(q, m); }
  float mean = s*(1.f/512.f);
  float rs = rsqrtf(q*(1.f/512.f) - mean*mean + 1e-5f);
  float t[8];
  #pragma unroll
  for(int e = 0; e < 8; e++) t[e] = (x[e]-mean)*rs*g1[lane*8+e] + b1[lane*8+e];
  float s2 = 0.f, q2 = 0.f;
  #pragma unroll
  for(int e = 0; e < 8; e++){ s2 += t[e]; q2 += t[e]*t[e]; }
  #pragma unroll
  for(int m = 1; m < 64; m <<= 1){ s2 += __shfl_xor(s2, m); q2 += __shfl_xor(q2, m); }
  float mean2 = s2*(1.f/512.f);
  float rs2 = rsqrtf(q2*(1.f/512.f) - mean2*mean2 + 1e-5f);
  float y[8];
  #pragma unroll
  for(int e = 0; e < 8; e++) y[e] = (t[e]-mean2)*rs2*g2[lane*8+e] + b2[lane*8+e];
  uint4 ov = { pack2(y[0],y[1]), pack2(y[2],y[3]), pack2(y[4],y[5]), pack2(y[6],y[7]) };
  *(uint4*)(out + (size_t)row*512 + lane*8) = ov;
}

// ---------------- 128x128-tile bf16 MFMA GEMM (big shapes) ----------------
// EPI bits: 1 = store bf16 (else f32), 2 = quick-gelu, 4 = add resid (f32)
template<int EPI>
__global__ __launch_bounds__(256) void gemm_bt_k(
    const u16* __restrict__ A, const u16* __restrict__ B,
    const float* __restrict__ bias, const float* __restrict__ resid,
    float* __restrict__ outF, u16* __restrict__ outB,
    int M, int N, int K, float scale)
{
  __shared__ __align__(16) u16 As[128*64];
  __shared__ __align__(16) u16 Bs[128*64];
  const int tid = threadIdx.x;
  const int lane = tid & 63, w = tid >> 6;
  const int m0 = blockIdx.y * 128, n0 = blockIdx.x * 128;
  const int wm = (w >> 1) * 64, wn = (w & 1) * 64;
  const int g = lane >> 4, q = lane & 15;
  f32x4 acc[4][4] = {};

  const int srow = w*32 + (lane >> 3);
  const int scol = (lane & 7) * 8;
  const u16* Abase = A + (size_t)(m0 + srow) * K + scol;
  const u16* Bbase = B + (size_t)(n0 + srow) * K + scol;

  for(int kt = 0; kt < K; kt += 64){
    #pragma unroll
    for(int c = 0; c < 4; c++){
      gload_lds16(Abase + (size_t)c*8*K + kt, &As[(w*32 + c*8) * 64]);
      gload_lds16(Bbase + (size_t)c*8*K + kt, &Bs[(w*32 + c*8) * 64]);
    }
    __syncthreads();
    #pragma unroll
    for(int kk = 0; kk < 2; kk++){
      s16x8 af[4], bf[4];
      #pragma unroll
      for(int mi = 0; mi < 4; mi++) af[mi] = *(const s16x8*)&As[(wm + mi*16 + q)*64 + kk*32 + g*8];
      #pragma unroll
      for(int ni = 0; ni < 4; ni++) bf[ni] = *(const s16x8*)&Bs[(wn + ni*16 + q)*64 + kk*32 + g*8];
      #pragma unroll
      for(int mi = 0; mi < 4; mi++)
        #pragma unroll
        for(int ni = 0; ni < 4; ni++)
          acc[mi][ni] = __builtin_amdgcn_mfma_f32_16x16x32_bf16(af[mi], bf[ni], acc[mi][ni], 0, 0, 0);
    }
    __syncthreads();
  }
  #pragma unroll
  for(int ni = 0; ni < 4; ni++){
    const int colg = n0 + wn + ni*16 + q;
    const float bia = bias[colg];
    #pragma unroll
    for(int mi = 0; mi < 4; mi++){
      #pragma unroll
      for(int r = 0; r < 4; r++){
        const int rowg = m0 + wm + mi*16 + g*4 + r;
        float v = (acc[mi][ni][r] + bia) * scale;
        if(EPI & 2){ v = v / (1.f + __expf(-1.702f * v)); }
        if(EPI & 4){ v += resid[(size_t)rowg * N + colg]; }
        if(EPI & 1){ outB[(size_t)rowg * N + colg] = f2bf(v); }
        else       { outF[(size_t)rowg * N + colg] = v; }
      }
    }
  }
}

// ---------------- 64x64-tile bf16 MFMA GEMM (small shapes, 4x grid density) ----------------
template<int EPI>
__global__ __launch_bounds__(256) void gemm64_k(
    const u16* __restrict__ A, const u16* __restrict__ B,
    const float* __restrict__ bias, const float* __restrict__ resid,
    float* __restrict__ outF, u16* __restrict__ outB,
    int M, int N, int K, float scale)
{
  __shared__ __align__(16) u16 As[64*64];
  __shared__ __align__(16) u16 Bs[64*64];
  const int tid = threadIdx.x;
  const int lane = tid & 63, w = tid >> 6;
  const int m0 = blockIdx.y * 64, n0 = blockIdx.x * 64;
  const int wm = (w >> 1) * 32, wn = (w & 1) * 32;
  const int g = lane >> 4, q = lane & 15;
  f32x4 acc[2][2] = {};

  const int srow = w*8 + (lane >> 3);   // rows 0..31 for c=0, +32 for c=1
  const int scol = (lane & 7) * 8;
  const u16* Abase = A + (size_t)(m0 + srow) * K + scol;
  const u16* Bbase = B + (size_t)(n0 + srow) * K + scol;

  for(int kt = 0; kt < K; kt += 64){
    #pragma unroll
    for(int c = 0; c < 2; c++){
      gload_lds16(Abase + (size_t)c*32*K + kt, &As[(c*32 + w*8) * 64]);
      gload_lds16(Bbase + (size_t)c*32*K + kt, &Bs[(c*32 + w*8) * 64]);
    }
    __syncthreads();
    #pragma unroll
    for(int kk = 0; kk < 2; kk++){
      s16x8 af[2], bf[2];
      #pragma unroll
      for(int mi = 0; mi < 2; mi++) af[mi] = *(const s16x8*)&As[(wm + mi*16 + q)*64 + kk*32 + g*8];
      #pragma unroll
      for(int ni = 0; ni < 2; ni++) bf[ni] = *(const s16x8*)&Bs[(wn + ni*16 + q)*64 + kk*32 + g*8];
      #pragma unroll
      for(int mi = 0; mi < 2; mi++)
        #pragma unroll
        for(int ni = 0; ni < 2; ni++)
          acc[mi][ni] = __builtin_amdgcn_mfma_f32_16x16x32_bf16(af[mi], bf[ni], acc[mi][ni], 0, 0, 0);
    }
    __syncthreads();
  }
  #pragma unroll
  for(int ni = 0; ni < 2; ni++){
    const int colg = n0 + wn + ni*16 + q;
    const float bia = bias[colg];
    #pragma unroll
    for(int mi = 0; mi < 2; mi++){
      #pragma unroll
      for(int r = 0; r < 4; r++){
        const int rowg = m0 + wm + mi*16 + g*4 + r;
        float v = (acc[mi][ni][r] + bia) * scale;
        if(EPI & 2){ v = v / (1.f + __expf(-1.702f * v)); }
        if(EPI & 4){ v += resid[(size_t)rowg * N + colg]; }
        if(EPI & 1){ outB[(size_t)rowg * N + colg] = f2bf(v); }
        else       { outF[(size_t)rowg * N + colg] = v; }
      }
    }
  }
}

// ---------------- perceiver flash attention, KV-split x8 ----------------
// V^T swizzle: byte = dd*64 + ((sj*2) ^ swz(dd)), swz(dd) = ((dd>>3)&3)<<4.
// Constraint: swz must be 16B-aligned and < 64 (row size) -> only bits 4-5.
// Write side: dd>>3 = sd -> swz varies across storing lanes (breaks old 16-way).
// Read side: dr = dt*16+q -> dr>>3 = dt*2+(q>>3) varies -> banks spread.
// (Round-3 bug: ((dd>>3)^dd)&7)<<4 reached bit 6 = 64 -> crossed rows / overflowed LDS.)
DEV int vt_swz(int dd){ return ((dd >> 3) & 3) << 4; }

DEV void stage_write_kv(u16* Ks, u16* VTs, int sj, int sd, uint4 kreg, uint4 vreg){
  *(uint4*)((char*)Ks + sj*256 + ((sd*16) ^ ((sj & 7) << 4))) = kreg;
  const u16* vp = (const u16*)&vreg;
  #pragma unroll
  for(int e = 0; e < 8; e++){
    int dd = sd*8 + e;
    *((u16*)((char*)VTs + dd*64 + ((sj*2) ^ vt_swz(dd)))) = vp[e];
  }
}

__global__ __launch_bounds__(512) void attn_pa_k(
    const u16* __restrict__ qb, const u16* __restrict__ kvx,
    const u16* __restrict__ kvl,
    float* __restrict__ o_part, float* __restrict__ m_part, float* __restrict__ l_part)
{
  const int h = blockIdx.x, b = blockIdx.y, s = blockIdx.z;
  const int bh = b*8 + h;
  const int c0 = s*16 + (s < 4 ? s : 4);
  const int nc = (s < 4) ? 17 : 16;
  const int tid = threadIdx.x;
  const int lane = tid & 63, w = tid >> 6;
  const int g = lane >> 4, q = lane & 15;
  __shared__ __align__(16) u16 Ks[32*128];   // [j][d] xor-swizzled
  __shared__ __align__(16) u16 VTs[128*32];  // [d][j] xor-swizzled

  s16x8 qf[4];
  const int q0 = w * 16;
  #pragma unroll
  for(int kk = 0; kk < 4; kk++)
    qf[kk] = *(const s16x8*)&qb[(size_t)(q0 + q)*1024 + h*128 + kk*32 + g*8];

  f32x4 oa[8] = {};
  float mrun = -1e30f, lsum = 0.f;

  const int sj = tid >> 4, sd = tid & 15;
  const int hk = h*128 + sd*8;

  uint4 kreg, vreg;
  {
    int jr = c0*32 + sj;
    const u16* p = (jr < 4096) ? (kvx + ((size_t)b*4096 + jr)*2048)
                               : (kvl + (size_t)(jr - 4096)*2048);
    kreg = *(const uint4*)(p + hk);
    vreg = *(const uint4*)(p + 1024 + hk);
  }
  stage_write_kv(Ks, VTs, sj, sd, kreg, vreg);

  for(int cc = 0; cc < nc; cc++){
    __syncthreads();
    uint4 kn, vn;
    if(cc + 1 < nc){
      int jr = (c0 + cc + 1)*32 + sj;
      const u16* p = (jr < 4096) ? (kvx + ((size_t)b*4096 + jr)*2048)
                                 : (kvl + (size_t)(jr - 4096)*2048);
      kn = *(const uint4*)(p + hk);
      vn = *(const uint4*)(p + 1024 + hk);
    }
    // sim^T = mfma(K, Q): C[j][q]
    f32x4 s0 = {}, s1 = {};
    #pragma unroll
    for(int kk = 0; kk < 4; kk++){
      const int r0 = q, r1 = 16 + q;
      s16x8 kf0 = *(const s16x8*)((const char*)Ks + r0*256 + ((kk*64 + g*16) ^ ((r0 & 7) << 4)));
      s16x8 kf1 = *(const s16x8*)((const char*)Ks + r1*256 + ((kk*64 + g*16) ^ ((r1 & 7) << 4)));
      s0 = __builtin_amdgcn_mfma_f32_16x16x32_bf16(kf0, qf[kk], s0, 0, 0, 0);
      s1 = __builtin_amdgcn_mfma_f32_16x16x32_bf16(kf1, qf[kk], s1, 0, 0, 0);
    }
    float cmax = fmaxf(fmaxf(fmaxf(s0[0], s0[1]), fmaxf(s0[2], s0[3])),
                       fmaxf(fmaxf(s1[0], s1[1]), fmaxf(s1[2], s1[3])));
    cmax = fmaxf(cmax, __shfl_xor(cmax, 16));
    cmax = fmaxf(cmax, __shfl_xor(cmax, 32));
    if(!__all(cmax <= mrun)){
      float nm = fmaxf(mrun, cmax);
      float sc = __expf(mrun - nm);
      #pragma unroll
      for(int dt = 0; dt < 8; dt++){
        oa[dt][0] *= sc; oa[dt][1] *= sc; oa[dt][2] *= sc; oa[dt][3] *= sc;
      }
      lsum *= sc; mrun = nm;
    }
    float p0 = __expf(s0[0]-mrun), p1 = __expf(s0[1]-mrun), p2 = __expf(s0[2]-mrun), p3 = __expf(s0[3]-mrun);
    float p4 = __expf(s1[0]-mrun), p5 = __expf(s1[1]-mrun), p6 = __expf(s1[2]-mrun), p7 = __expf(s1[3]-mrun);
    float cs = ((p0+p1)+(p2+p3)) + ((p4+p5)+(p6+p7));
    cs += __shfl_xor(cs, 16); cs += __shfl_xor(cs, 32);
    lsum += cs;
    // redistribute P^T into PV B-fragment
    u32 t0a = pack2(p0,p1), t0b = pack2(p2,p3), t1a = pack2(p4,p5), t1b = pack2(p6,p7);
    int srcA = ((g & 1) * 2) * 16 + q;
    int srcB = srcA + 16;
    u32 a0 = (u32)__shfl((int)t0a, srcA), b0 = (u32)__shfl((int)t1a, srcA);
    u32 a1 = (u32)__shfl((int)t0b, srcA), b1 = (u32)__shfl((int)t1b, srcA);
    u32 a2 = (u32)__shfl((int)t0a, srcB), b2 = (u32)__shfl((int)t1a, srcB);
    u32 a3 = (u32)__shfl((int)t0b, srcB), b3 = (u32)__shfl((int)t1b, srcB);
    bool lo = (lane < 32);
    uint4 pu;
    pu.x = lo ? a0 : b0; pu.y = lo ? a1 : b1; pu.z = lo ? a2 : b2; pu.w = lo ? a3 : b3;
    s16x8 pf = __builtin_bit_cast(s16x8, pu);
    // o^T[d][q] += mfma(V^T, P)
    #pragma unroll
    for(int dt = 0; dt < 8; dt++){
      const int dr = dt*16 + q;
      s16x8 vf = *(const s16x8*)((const char*)VTs + dr*64 + ((g*16) ^ vt_swz(dr)));
      oa[dt] = __builtin_amdgcn_mfma_f32_16x16x32_bf16(vf, pf, oa[dt], 0, 0, 0);
    }
    __syncthreads();
    if(cc + 1 < nc){ kreg = kn; vreg = vn; stage_write_kv(Ks, VTs, sj, sd, kreg, vreg); }
  }
  // store partials (un-normalized o, plus m/l per q-row)
  const size_t rowbase = ((size_t)(s*64 + bh)*128 + q0 + q);
  #pragma unroll
  for(int dt = 0; dt < 8; dt++){
    float4 v = { oa[dt][0], oa[dt][1], oa[dt][2], oa[dt][3] };
    *(float4*)&o_part[rowbase*128 + dt*16 + g*4] = v;
  }
  if(g == 0){ m_part[rowbase] = mrun; l_part[rowbase] = lsum; }
}

// ---------------- flash combine over 8 splits ----------------
__global__ __launch_bounds__(128) void attn_comb_k(
    const float* __restrict__ o_part, const float* __restrict__ m_part,
    const float* __restrict__ l_part, u16* __restrict__ opa)
{
  const int row = blockIdx.x;          // bh*128 + q, 0..8191
  const int d = threadIdx.x;
  const int bh = row >> 7, q = row & 127;
  const int b = bh >> 3, h = bh & 7;
  float ms[8];
  float M = -1e30f;
  #pragma unroll
  for(int s = 0; s < 8; s++){
    ms[s] = m_part[(size_t)(s*64 + bh)*128 + q];
    M = fmaxf(M, ms[s]);
  }
  float L = 0.f, acc = 0.f;
  #pragma unroll
  for(int s = 0; s < 8; s++){
    float wgt = __expf(ms[s] - M);
    L += l_part[(size_t)(s*64 + bh)*128 + q] * wgt;
    acc += o_part[((size_t)(s*64 + bh)*128 + q)*128 + d] * wgt;
  }
  opa[(size_t)(b*128 + q)*1024 + h*128 + d] = f2bf(acc / L);
}

// ---------------- MHA over batch axis (i,j = 8) ----------------
__global__ __launch_bounds__(64) void attn2_k(const float* __restrict__ qkv2, u16* __restrict__ o2){
  const int n = blockIdx.x, h = blockIdx.y;
  const int lane = threadIdx.x;
  __shared__ float qs[8][64], ks[8][64], vs[8][64], as_[8][8];
  #pragma unroll
  for(int i = 0; i < 8; i++){
    size_t base = (size_t)(i*128 + n) * 1536 + h*64 + lane;
    qs[i][lane] = qkv2[base] * 0.125f;
    ks[i][lane] = qkv2[base + 512];
    vs[i][lane] = qkv2[base + 1024];
  }
  __syncthreads();
  const int i = lane >> 3, j = lane & 7;
  float s = 0.f;
  #pragma unroll
  for(int d = 0; d < 64; d++) s += qs[i][d] * ks[j][d];
  float mx = s;
  mx = fmaxf(mx, __shfl_xor(mx, 1)); mx = fmaxf(mx, __shfl_xor(mx, 2)); mx = fmaxf(mx, __shfl_xor(mx, 4));
  float p = __expf(s - mx);
  float ps = p;
  ps += __shfl_xor(ps, 1); ps += __shfl_xor(ps, 2); ps += __shfl_xor(ps, 4);
  as_[i][j] = p / ps;
  __syncthreads();
  const int d0 = (lane & 7) * 8, i2 = lane >> 3;
  #pragma unroll
  for(int dd = 0; dd < 8; dd++){
    float acc = 0.f;
    #pragma unroll
    for(int jj = 0; jj < 8; jj++) acc += as_[i2][jj] * vs[jj][d0 + dd];
    o2[(size_t)(i2*128 + n) * 512 + h*64 + d0 + dd] = f2bf(acc);
  }
}

extern "C" void kernel_launch(void* const* d_in, const int* in_sizes, int n_in,
                              void* d_out, int out_size, void* d_ws, size_t ws_size,
                              hipStream_t stream){
  const float* visual  = (const float*)d_in[0];
  const float* latents = (const float*)d_in[1];
  const float* nl_g    = (const float*)d_in[2];
  const float* nl_b    = (const float*)d_in[3];
  const float* pa_nm_g = (const float*)d_in[4];
  const float* pa_nm_b = (const float*)d_in[5];
  const float* pa_nl_g = (const float*)d_in[6];
  const float* pa_nl_b = (const float*)d_in[7];
  const float* Wq  = (const float*)d_in[8];
  const float* bq  = (const float*)d_in[9];
  const float* Wkv = (const float*)d_in[10];
  const float* bkv = (const float*)d_in[11];
  const float* Wo  = (const float*)d_in[12];
  const float* bo  = (const float*)d_in[13];
  const float* Wip = (const float*)d_in[14];
  const float* bip = (const float*)d_in[15];
  const float* Wop = (const float*)d_in[16];
  const float* bop = (const float*)d_in[17];
  const float* ln1_g = (const float*)d_in[18];
  const float* ln1_b = (const float*)d_in[19];
  const float* ln2_g = (const float*)d_in[20];
  const float* ln2_b = (const float*)d_in[21];
  const float* Wfc = (const float*)d_in[22];
  const float* bfc = (const float*)d_in[23];
  const float* Wpj = (const float*)d_in[24];
  const float* bpj = (const float*)d_in[25];
  float* out = (float*)d_out;

  char* p = (char*)d_ws;
  auto alloc = [&](size_t n)->char*{ char* r = p; p += (n + 255) & ~(size_t)255; return r; };
  u16* Wq_b  = (u16*)alloc((size_t)1024*512*2);
  u16* Wkv_b = (u16*)alloc((size_t)2048*512*2);
  u16* Wo_b  = (u16*)alloc((size_t)512*1024*2);
  u16* Wip_b = (u16*)alloc((size_t)1536*512*2);
  u16* Wop_b = (u16*)alloc((size_t)512*512*2);
  u16* Wfc_b = (u16*)alloc((size_t)2048*512*2);
  u16* Wpj_b = (u16*)alloc((size_t)512*2048*2);
  u16* l_b   = (u16*)alloc((size_t)128*512*2);
  u16* q_b   = (u16*)alloc((size_t)128*1024*2);
  u16* kvl_b = (u16*)alloc((size_t)128*2048*2);
  u16* xln_b = (u16*)alloc((size_t)32768*512*2);   // 33,554,432 B; dead after kvx GEMM
  u16* kvx_b = (u16*)alloc((size_t)32768*2048*2);
  u16* opa_b = (u16*)alloc((size_t)1024*1024*2);
  float* lat1 = (float*)alloc((size_t)1024*512*4);
  u16* y_b   = (u16*)alloc((size_t)1024*512*2);
  float* qkv2 = (float*)alloc((size_t)1024*1536*4);
  u16* o2_b  = (u16*)alloc((size_t)1024*512*2);
  float* lat2 = (float*)alloc((size_t)1024*512*4);
  u16* z_b   = (u16*)alloc((size_t)1024*512*2);
  u16* h1_b  = (u16*)alloc((size_t)1024*2048*2);
  float* m_part = (float*)alloc((size_t)8*64*128*4);
  float* l_part = (float*)alloc((size_t)8*64*128*4);
  // o_part [8 splits][64 bh][128 q][128 d] f32 = 33,554,432 B: aliases dead xln_b exactly.
  float* o_part = (float*)xln_b;

  {
    CvtArgs a;
    a.src[0]=Wq;  a.dst[0]=Wq_b;  a.n[0]=1024*512;
    a.src[1]=Wkv; a.dst[1]=Wkv_b; a.n[1]=2048*512;
    a.src[2]=Wo;  a.dst[2]=Wo_b;  a.n[2]=512*1024;
    a.src[3]=Wip; a.dst[3]=Wip_b; a.n[3]=1536*512;
    a.src[4]=Wop; a.dst[4]=Wop_b; a.n[4]=512*512;
    a.src[5]=Wfc; a.dst[5]=Wfc_b; a.n[5]=2048*512;
    a.src[6]=Wpj; a.dst[6]=Wpj_b; a.n[6]=512*2048;
    cvt_all_k<<<dim3(256, 7), 256, 0, stream>>>(a);
  }

  lat_ln2_k<<<128, 64, 0, stream>>>(latents, nl_g, nl_b, pa_nl_g, pa_nl_b, l_b);
  ln_rows_k<<<32768, 64, 0, stream>>>(visual, pa_nm_g, pa_nm_b, xln_b);

  // q = (l @ Wq^T + bq) * dh^-0.5   -> bf16 [128,1024]
  gemm64_k<1><<<dim3(16, 2), 256, 0, stream>>>(l_b, Wq_b, bq, nullptr, nullptr, q_b,
                                               128, 1024, 512, 0.08838834764831845f);
  // kv_l = l @ Wkv^T + bkv          -> bf16 [128,2048]
  gemm64_k<1><<<dim3(32, 2), 256, 0, stream>>>(l_b, Wkv_b, bkv, nullptr, nullptr, kvl_b,
                                               128, 2048, 512, 1.f);
  // kv_x = ln(visual) @ Wkv^T + bkv -> bf16 [32768,2048]  (must finish before o_part reuse)
  gemm_bt_k<1><<<dim3(16, 256), 256, 0, stream>>>(xln_b, Wkv_b, bkv, nullptr, nullptr, kvx_b,
                                                  32768, 2048, 512, 1.f);
  // flash attention, 8 KV-splits, then combine
  attn_pa_k<<<dim3(8, 8, 8), 512, 0, stream>>>(q_b, kvx_b, kvl_b, o_part, m_part, l_part);
  attn_comb_k<<<8192, 128, 0, stream>>>(o_part, m_part, l_part, opa_b);
  // lat1 = o @ Wo^T + bo -> f32 [1024,512]
  gemm64_k<0><<<dim3(8, 16), 256, 0, stream>>>(opa_b, Wo_b, bo, nullptr, lat1, nullptr,
                                               1024, 512, 1024, 1.f);
  ln_rows_k<<<1024, 64, 0, stream>>>(lat1, ln1_g, ln1_b, y_b);
  // qkv2 = y @ in_proj^T + b -> f32 [1024,1536]
  gemm64_k<0><<<dim3(24, 16), 256, 0, stream>>>(y_b, Wip_b, bip, nullptr, qkv2, nullptr,
                                                1024, 1536, 512, 1.f);
  attn2_k<<<dim3(128, 8), 64, 0, stream>>>(qkv2, o2_b);
  // lat2 = lat1 + o2 @ out_proj^T + b -> f32
  gemm64_k<4><<<dim3(8, 16), 256, 0, stream>>>(o2_b, Wop_b, bop, lat1, lat2, nullptr,
                                               1024, 512, 512, 1.f);
  ln_rows_k<<<1024, 64, 0, stream>>>(lat2, ln2_g, ln2_b, z_b);
  // h1 = qgelu(z @ Wfc^T + bfc) -> bf16 [1024,2048]
  gemm64_k<3><<<dim3(32, 16), 256, 0, stream>>>(z_b, Wfc_b, bfc, nullptr, nullptr, h1_b,
                                                1024, 2048, 512, 1.f);
  // out = lat2 + h1 @ Wproj^T + bproj -> f32 [1024,512]
  gemm64_k<4><<<dim3(8, 16), 256, 0, stream>>>(h1_b, Wpj_b, bpj, lat2, out, nullptr,
                                               1024, 512, 2048, 1.f);
}

// Round 11
// 396.478 us; speedup vs baseline: 1.7152x; 1.0574x over previous
//
#include <hip/hip_runtime.h>
#include <stdint.h>

typedef unsigned int u32;
typedef unsigned short u16;
typedef __attribute__((ext_vector_type(4))) float f32x4;
typedef __attribute__((ext_vector_type(8))) short s16x8;

#define DEV static __device__ __forceinline__

DEV u16 f2bf(float x){
  u32 u = __builtin_bit_cast(u32, x);
  u32 r = u + 0x7FFFu + ((u >> 16) & 1u);
  return (u16)(r >> 16);
}
DEV float bf2f(u16 b){ return __builtin_bit_cast(float, (u32)b << 16); }
DEV u32 pack2(float a, float b){ return ((u32)f2bf(b) << 16) | (u32)f2bf(a); }

DEV void gload_lds16(const void* g, void* l){
  __builtin_amdgcn_global_load_lds(
      (const __attribute__((address_space(1))) void*)g,
      (__attribute__((address_space(3))) void*)l,
      16, 0, 0);
}

// ---------------- fused weight f32 -> bf16 (7 segments, 1 launch) ----------------
struct CvtArgs { const float* src[7]; u16* dst[7]; int n[7]; };
__global__ void cvt_all_k(CvtArgs a){
  const int seg = blockIdx.y;
  const int n = a.n[seg];
  const float* __restrict__ in = a.src[seg];
  u16* __restrict__ out = a.dst[seg];
  int i = (blockIdx.x * blockDim.x + threadIdx.x) * 4;
  const int stride = gridDim.x * blockDim.x * 4;
  for(; i < n; i += stride){
    float4 v = *(const float4*)(in + i);
    u32 lo = pack2(v.x, v.y), hi = pack2(v.z, v.w);
    *(uint2*)(out + i) = make_uint2(lo, hi);
  }
}

// ---------------- LN over rows of 512, f32 in -> bf16 out ----------------
__global__ __launch_bounds__(64) void ln_rows_k(const float* __restrict__ in,
    const float* __restrict__ gw, const float* __restrict__ bw, u16* __restrict__ out){
  const int row = blockIdx.x, lane = threadIdx.x;
  const float* p = in + (size_t)row * 512 + lane * 8;
  float4 a = *(const float4*)p;
  float4 b = *(const float4*)(p + 4);
  float x[8] = {a.x,a.y,a.z,a.w,b.x,b.y,b.z,b.w};
  float s = 0.f, q = 0.f;
  #pragma unroll
  for(int e = 0; e < 8; e++){ s += x[e]; q += x[e]*x[e]; }
  #pragma unroll
  for(int m = 1; m < 64; m <<= 1){ s += __shfl_xor(s, m); q += __shfl_xor(q, m); }
  float mean = s * (1.f/512.f);
  float rs = rsqrtf(q * (1.f/512.f) - mean*mean + 1e-5f);
  const float* gp = gw + lane*8; const float* bp = bw + lane*8;
  float4 g0 = *(const float4*)gp, g1 = *(const float4*)(gp+4);
  float4 b0 = *(const float4*)bp, b1 = *(const float4*)(bp+4);
  float gg[8] = {g0.x,g0.y,g0.z,g0.w,g1.x,g1.y,g1.z,g1.w};
  float bb[8] = {b0.x,b0.y,b0.z,b0.w,b1.x,b1.y,b1.z,b1.w};
  float y[8];
  #pragma unroll
  for(int e = 0; e < 8; e++) y[e] = (x[e]-mean)*rs*gg[e] + bb[e];
  uint4 ov = { pack2(y[0],y[1]), pack2(y[2],y[3]), pack2(y[4],y[5]), pack2(y[6],y[7]) };
  *(uint4*)(out + (size_t)row*512 + lane*8) = ov;
}

// ---------------- double LN of latents ----------------
__global__ __launch_bounds__(64) void lat_ln2_k(const float* __restrict__ lp,
    const float* __restrict__ g1, const float* __restrict__ b1,
    const float* __restrict__ g2, const float* __restrict__ b2, u16* __restrict__ out){
  const int row = blockIdx.x, lane = threadIdx.x;
  const float* p = lp + (size_t)row*512 + lane*8;
  float4 a = *(const float4*)p;
  float4 b4 = *(const float4*)(p + 4);
  float x[8] = {a.x,a.y,a.z,a.w,b4.x,b4.y,b4.z,b4.w};
  float s = 0.f, q = 0.f;
  #pragma unroll
  for(int e = 0; e < 8; e++){ s += x[e]; q += x[e]*x[e]; }
  #pragma unroll
  for(int m = 1; m < 64; m <<= 1){ s += __shfl_xor(s, m); q += __shfl_xor(q, m); }
  float mean = s*(1.f/512.f);
  float rs = rsqrtf(q*(1.f/512.f) - mean*mean + 1e-5f);
  float t[8];
  #pragma unroll
  for(int e = 0; e < 8; e++) t[e] = (x[e]-mean)*rs*g1[lane*8+e] + b1[lane*8+e];
  float s2 = 0.f, q2 = 0.f;
  #pragma unroll
  for(int e = 0; e < 8; e++){ s2 += t[e]; q2 += t[e]*t[e]; }
  #pragma unroll
  for(int m = 1; m < 64; m <<= 1){ s2 += __shfl_xor(s2, m); q2 += __shfl_xor(q2, m); }
  float mean2 = s2*(1.f/512.f);
  float rs2 = rsqrtf(q2*(1.f/512.f) - mean2*mean2 + 1e-5f);
  float y[8];
  #pragma unroll
  for(int e = 0; e < 8; e++) y[e] = (t[e]-mean2)*rs2*g2[lane*8+e] + b2[lane*8+e];
  uint4 ov = { pack2(y[0],y[1]), pack2(y[2],y[3]), pack2(y[4],y[5]), pack2(y[6],y[7]) };
  *(uint4*)(out + (size_t)row*512 + lane*8) = ov;
}

// ---------------- 128x128-tile bf16 MFMA GEMM (big shapes) ----------------
// LDS swizzle (rule 21: both-sides-or-neither with global_load_lds):
//   LDS dest stays linear; the GLOBAL source column slot is permuted s -> s ^ (row&7),
//   so LDS slot s of row r holds global col-block s ^ (r&7). Fragment read applies
//   the same XOR: cb -> cb ^ (q&7). Spreads the old 16-way ds_read_b128 conflict
//   (row stride 128B = 32 banks) to the structural 8-slot floor.
// EPI bits: 1 = store bf16 (else f32), 2 = quick-gelu, 4 = add resid (f32)
template<int EPI>
__global__ __launch_bounds__(256) void gemm_bt_k(
    const u16* __restrict__ A, const u16* __restrict__ B,
    const float* __restrict__ bias, const float* __restrict__ resid,
    float* __restrict__ outF, u16* __restrict__ outB,
    int M, int N, int K, float scale)
{
  __shared__ __align__(16) u16 As[128*64];
  __shared__ __align__(16) u16 Bs[128*64];
  const int tid = threadIdx.x;
  const int lane = tid & 63, w = tid >> 6;
  const int m0 = blockIdx.y * 128, n0 = blockIdx.x * 128;
  const int wm = (w >> 1) * 64, wn = (w & 1) * 64;
  const int g = lane >> 4, q = lane & 15;
  f32x4 acc[4][4] = {};

  const int srow = w*32 + (lane >> 3);
  const int scol = (((lane & 7) ^ ((lane >> 3) & 7)) * 8);   // pre-swizzled source slot
  const u16* Abase = A + (size_t)(m0 + srow) * K + scol;
  const u16* Bbase = B + (size_t)(n0 + srow) * K + scol;

  for(int kt = 0; kt < K; kt += 64){
    #pragma unroll
    for(int c = 0; c < 4; c++){
      gload_lds16(Abase + (size_t)c*8*K + kt, &As[(w*32 + c*8) * 64]);
      gload_lds16(Bbase + (size_t)c*8*K + kt, &Bs[(w*32 + c*8) * 64]);
    }
    __syncthreads();
    #pragma unroll
    for(int kk = 0; kk < 2; kk++){
      s16x8 af[4], bf[4];
      const int cb = ((kk*4 + g) ^ (q & 7)) * 8;             // swizzled read slot
      #pragma unroll
      for(int mi = 0; mi < 4; mi++) af[mi] = *(const s16x8*)&As[(wm + mi*16 + q)*64 + cb];
      #pragma unroll
      for(int ni = 0; ni < 4; ni++) bf[ni] = *(const s16x8*)&Bs[(wn + ni*16 + q)*64 + cb];
      #pragma unroll
      for(int mi = 0; mi < 4; mi++)
        #pragma unroll
        for(int ni = 0; ni < 4; ni++)
          acc[mi][ni] = __builtin_amdgcn_mfma_f32_16x16x32_bf16(af[mi], bf[ni], acc[mi][ni], 0, 0, 0);
    }
    __syncthreads();
  }
  #pragma unroll
  for(int ni = 0; ni < 4; ni++){
    const int colg = n0 + wn + ni*16 + q;
    const float bia = bias[colg];
    #pragma unroll
    for(int mi = 0; mi < 4; mi++){
      #pragma unroll
      for(int r = 0; r < 4; r++){
        const int rowg = m0 + wm + mi*16 + g*4 + r;
        float v = (acc[mi][ni][r] + bia) * scale;
        if(EPI & 2){ v = v / (1.f + __expf(-1.702f * v)); }
        if(EPI & 4){ v += resid[(size_t)rowg * N + colg]; }
        if(EPI & 1){ outB[(size_t)rowg * N + colg] = f2bf(v); }
        else       { outF[(size_t)rowg * N + colg] = v; }
      }
    }
  }
}

// ---------------- 64x64-tile bf16 MFMA GEMM (small shapes, 4x grid density) ----------------
template<int EPI>
__global__ __launch_bounds__(256) void gemm64_k(
    const u16* __restrict__ A, const u16* __restrict__ B,
    const float* __restrict__ bias, const float* __restrict__ resid,
    float* __restrict__ outF, u16* __restrict__ outB,
    int M, int N, int K, float scale)
{
  __shared__ __align__(16) u16 As[64*64];
  __shared__ __align__(16) u16 Bs[64*64];
  const int tid = threadIdx.x;
  const int lane = tid & 63, w = tid >> 6;
  const int m0 = blockIdx.y * 64, n0 = blockIdx.x * 64;
  const int wm = (w >> 1) * 32, wn = (w & 1) * 32;
  const int g = lane >> 4, q = lane & 15;
  f32x4 acc[2][2] = {};

  const int srow = w*8 + (lane >> 3);   // rows 0..31 for c=0, +32 for c=1
  const int scol = (((lane & 7) ^ ((lane >> 3) & 7)) * 8);   // pre-swizzled source slot
  const u16* Abase = A + (size_t)(m0 + srow) * K + scol;
  const u16* Bbase = B + (size_t)(n0 + srow) * K + scol;

  for(int kt = 0; kt < K; kt += 64){
    #pragma unroll
    for(int c = 0; c < 2; c++){
      gload_lds16(Abase + (size_t)c*32*K + kt, &As[(c*32 + w*8) * 64]);
      gload_lds16(Bbase + (size_t)c*32*K + kt, &Bs[(c*32 + w*8) * 64]);
    }
    __syncthreads();
    #pragma unroll
    for(int kk = 0; kk < 2; kk++){
      s16x8 af[2], bf[2];
      const int cb = ((kk*4 + g) ^ (q & 7)) * 8;             // swizzled read slot
      #pragma unroll
      for(int mi = 0; mi < 2; mi++) af[mi] = *(const s16x8*)&As[(wm + mi*16 + q)*64 + cb];
      #pragma unroll
      for(int ni = 0; ni < 2; ni++) bf[ni] = *(const s16x8*)&Bs[(wn + ni*16 + q)*64 + cb];
      #pragma unroll
      for(int mi = 0; mi < 2; mi++)
        #pragma unroll
        for(int ni = 0; ni < 2; ni++)
          acc[mi][ni] = __builtin_amdgcn_mfma_f32_16x16x32_bf16(af[mi], bf[ni], acc[mi][ni], 0, 0, 0);
    }
    __syncthreads();
  }
  #pragma unroll
  for(int ni = 0; ni < 2; ni++){
    const int colg = n0 + wn + ni*16 + q;
    const float bia = bias[colg];
    #pragma unroll
    for(int mi = 0; mi < 2; mi++){
      #pragma unroll
      for(int r = 0; r < 4; r++){
        const int rowg = m0 + wm + mi*16 + g*4 + r;
        float v = (acc[mi][ni][r] + bia) * scale;
        if(EPI & 2){ v = v / (1.f + __expf(-1.702f * v)); }
        if(EPI & 4){ v += resid[(size_t)rowg * N + colg]; }
        if(EPI & 1){ outB[(size_t)rowg * N + colg] = f2bf(v); }
        else       { outF[(size_t)rowg * N + colg] = v; }
      }
    }
  }
}

// ---------------- perceiver flash attention, KV-split x8 ----------------
// V^T swizzle: byte = dd*64 + ((sj*2) ^ swz(dd)), swz(dd) = ((dd>>3)&3)<<4.
// Constraint: swz must be 16B-aligned and < 64 (row size) -> only bits 4-5.
DEV int vt_swz(int dd){ return ((dd >> 3) & 3) << 4; }

DEV void stage_write_kv(u16* Ks, u16* VTs, int sj, int sd, uint4 kreg, uint4 vreg){
  *(uint4*)((char*)Ks + sj*256 + ((sd*16) ^ ((sj & 7) << 4))) = kreg;
  const u16* vp = (const u16*)&vreg;
  #pragma unroll
  for(int e = 0; e < 8; e++){
    int dd = sd*8 + e;
    *((u16*)((char*)VTs + dd*64 + ((sj*2) ^ vt_swz(dd)))) = vp[e];
  }
}

__global__ __launch_bounds__(512) void attn_pa_k(
    const u16* __restrict__ qb, const u16* __restrict__ kvx,
    const u16* __restrict__ kvl,
    float* __restrict__ o_part, float* __restrict__ m_part, float* __restrict__ l_part)
{
  const int h = blockIdx.x, b = blockIdx.y, s = blockIdx.z;
  const int bh = b*8 + h;
  const int c0 = s*16 + (s < 4 ? s : 4);
  const int nc = (s < 4) ? 17 : 16;
  const int tid = threadIdx.x;
  const int lane = tid & 63, w = tid >> 6;
  const int g = lane >> 4, q = lane & 15;
  __shared__ __align__(16) u16 Ks[32*128];   // [j][d] xor-swizzled
  __shared__ __align__(16) u16 VTs[128*32];  // [d][j] xor-swizzled

  s16x8 qf[4];
  const int q0 = w * 16;
  #pragma unroll
  for(int kk = 0; kk < 4; kk++)
    qf[kk] = *(const s16x8*)&qb[(size_t)(q0 + q)*1024 + h*128 + kk*32 + g*8];

  f32x4 oa[8] = {};
  float mrun = -1e30f, lsum = 0.f;

  const int sj = tid >> 4, sd = tid & 15;
  const int hk = h*128 + sd*8;

  uint4 kreg, vreg;
  {
    int jr = c0*32 + sj;
    const u16* p = (jr < 4096) ? (kvx + ((size_t)b*4096 + jr)*2048)
                               : (kvl + (size_t)(jr - 4096)*2048);
    kreg = *(const uint4*)(p + hk);
    vreg = *(const uint4*)(p + 1024 + hk);
  }
  stage_write_kv(Ks, VTs, sj, sd, kreg, vreg);

  for(int cc = 0; cc < nc; cc++){
    __syncthreads();
    uint4 kn, vn;
    if(cc + 1 < nc){
      int jr = (c0 + cc + 1)*32 + sj;
      const u16* p = (jr < 4096) ? (kvx + ((size_t)b*4096 + jr)*2048)
                                 : (kvl + (size_t)(jr - 4096)*2048);
      kn = *(const uint4*)(p + hk);
      vn = *(const uint4*)(p + 1024 + hk);
    }
    // sim^T = mfma(K, Q): C[j][q]
    f32x4 s0 = {}, s1 = {};
    #pragma unroll
    for(int kk = 0; kk < 4; kk++){
      const int r0 = q, r1 = 16 + q;
      s16x8 kf0 = *(const s16x8*)((const char*)Ks + r0*256 + ((kk*64 + g*16) ^ ((r0 & 7) << 4)));
      s16x8 kf1 = *(const s16x8*)((const char*)Ks + r1*256 + ((kk*64 + g*16) ^ ((r1 & 7) << 4)));
      s0 = __builtin_amdgcn_mfma_f32_16x16x32_bf16(kf0, qf[kk], s0, 0, 0, 0);
      s1 = __builtin_amdgcn_mfma_f32_16x16x32_bf16(kf1, qf[kk], s1, 0, 0, 0);
    }
    float cmax = fmaxf(fmaxf(fmaxf(s0[0], s0[1]), fmaxf(s0[2], s0[3])),
                       fmaxf(fmaxf(s1[0], s1[1]), fmaxf(s1[2], s1[3])));
    cmax = fmaxf(cmax, __shfl_xor(cmax, 16));
    cmax = fmaxf(cmax, __shfl_xor(cmax, 32));
    if(!__all(cmax <= mrun)){
      float nm = fmaxf(mrun, cmax);
      float sc = __expf(mrun - nm);
      #pragma unroll
      for(int dt = 0; dt < 8; dt++){
        oa[dt][0] *= sc; oa[dt][1] *= sc; oa[dt][2] *= sc; oa[dt][3] *= sc;
      }
      lsum *= sc; mrun = nm;
    }
    float p0 = __expf(s0[0]-mrun), p1 = __expf(s0[1]-mrun), p2 = __expf(s0[2]-mrun), p3 = __expf(s0[3]-mrun);
    float p4 = __expf(s1[0]-mrun), p5 = __expf(s1[1]-mrun), p6 = __expf(s1[2]-mrun), p7 = __expf(s1[3]-mrun);
    float cs = ((p0+p1)+(p2+p3)) + ((p4+p5)+(p6+p7));
    cs += __shfl_xor(cs, 16); cs += __shfl_xor(cs, 32);
    lsum += cs;
    // redistribute P^T into PV B-fragment
    u32 t0a = pack2(p0,p1), t0b = pack2(p2,p3), t1a = pack2(p4,p5), t1b = pack2(p6,p7);
    int srcA = ((g & 1) * 2) * 16 + q;
    int srcB = srcA + 16;
    u32 a0 = (u32)__shfl((int)t0a, srcA), b0 = (u32)__shfl((int)t1a, srcA);
    u32 a1 = (u32)__shfl((int)t0b, srcA), b1 = (u32)__shfl((int)t1b, srcA);
    u32 a2 = (u32)__shfl((int)t0a, srcB), b2 = (u32)__shfl((int)t1a, srcB);
    u32 a3 = (u32)__shfl((int)t0b, srcB), b3 = (u32)__shfl((int)t1b, srcB);
    bool lo = (lane < 32);
    uint4 pu;
    pu.x = lo ? a0 : b0; pu.y = lo ? a1 : b1; pu.z = lo ? a2 : b2; pu.w = lo ? a3 : b3;
    s16x8 pf = __builtin_bit_cast(s16x8, pu);
    // o^T[d][q] += mfma(V^T, P)
    #pragma unroll
    for(int dt = 0; dt < 8; dt++){
      const int dr = dt*16 + q;
      s16x8 vf = *(const s16x8*)((const char*)VTs + dr*64 + ((g*16) ^ vt_swz(dr)));
      oa[dt] = __builtin_amdgcn_mfma_f32_16x16x32_bf16(vf, pf, oa[dt], 0, 0, 0);
    }
    __syncthreads();
    if(cc + 1 < nc){ kreg = kn; vreg = vn; stage_write_kv(Ks, VTs, sj, sd, kreg, vreg); }
  }
  // store partials (un-normalized o, plus m/l per q-row)
  const size_t rowbase = ((size_t)(s*64 + bh)*128 + q0 + q);
  #pragma unroll
  for(int dt = 0; dt < 8; dt++){
    float4 v = { oa[dt][0], oa[dt][1], oa[dt][2], oa[dt][3] };
    *(float4*)&o_part[rowbase*128 + dt*16 + g*4] = v;
  }
  if(g == 0){ m_part[rowbase] = mrun; l_part[rowbase] = lsum; }
}

// ---------------- flash combine over 8 splits ----------------
__global__ __launch_bounds__(128) void attn_comb_k(
    const float* __restrict__ o_part, const float* __restrict__ m_part,
    const float* __restrict__ l_part, u16* __restrict__ opa)
{
  const int row = blockIdx.x;          // bh*128 + q, 0..8191
  const int d = threadIdx.x;
  const int bh = row >> 7, q = row & 127;
  const int b = bh >> 3, h = bh & 7;
  float ms[8];
  float M = -1e30f;
  #pragma unroll
  for(int s = 0; s < 8; s++){
    ms[s] = m_part[(size_t)(s*64 + bh)*128 + q];
    M = fmaxf(M, ms[s]);
  }
  float L = 0.f, acc = 0.f;
  #pragma unroll
  for(int s = 0; s < 8; s++){
    float wgt = __expf(ms[s] - M);
    L += l_part[(size_t)(s*64 + bh)*128 + q] * wgt;
    acc += o_part[((size_t)(s*64 + bh)*128 + q)*128 + d] * wgt;
  }
  opa[(size_t)(b*128 + q)*1024 + h*128 + d] = f2bf(acc / L);
}

// ---------------- MHA over batch axis (i,j = 8) ----------------
__global__ __launch_bounds__(64) void attn2_k(const float* __restrict__ qkv2, u16* __restrict__ o2){
  const int n = blockIdx.x, h = blockIdx.y;
  const int lane = threadIdx.x;
  __shared__ float qs[8][64], ks[8][64], vs[8][64], as_[8][8];
  #pragma unroll
  for(int i = 0; i < 8; i++){
    size_t base = (size_t)(i*128 + n) * 1536 + h*64 + lane;
    qs[i][lane] = qkv2[base] * 0.125f;
    ks[i][lane] = qkv2[base + 512];
    vs[i][lane] = qkv2[base + 1024];
  }
  __syncthreads();
  const int i = lane >> 3, j = lane & 7;
  float s = 0.f;
  #pragma unroll
  for(int d = 0; d < 64; d++) s += qs[i][d] * ks[j][d];
  float mx = s;
  mx = fmaxf(mx, __shfl_xor(mx, 1)); mx = fmaxf(mx, __shfl_xor(mx, 2)); mx = fmaxf(mx, __shfl_xor(mx, 4));
  float p = __expf(s - mx);
  float ps = p;
  ps += __shfl_xor(ps, 1); ps += __shfl_xor(ps, 2); ps += __shfl_xor(ps, 4);
  as_[i][j] = p / ps;
  __syncthreads();
  const int d0 = (lane & 7) * 8, i2 = lane >> 3;
  #pragma unroll
  for(int dd = 0; dd < 8; dd++){
    float acc = 0.f;
    #pragma unroll
    for(int jj = 0; jj < 8; jj++) acc += as_[i2][jj] * vs[jj][d0 + dd];
    o2[(size_t)(i2*128 + n) * 512 + h*64 + d0 + dd] = f2bf(acc);
  }
}

extern "C" void kernel_launch(void* const* d_in, const int* in_sizes, int n_in,
                              void* d_out, int out_size, void* d_ws, size_t ws_size,
                              hipStream_t stream){
  const float* visual  = (const float*)d_in[0];
  const float* latents = (const float*)d_in[1];
  const float* nl_g    = (const float*)d_in[2];
  const float* nl_b    = (const float*)d_in[3];
  const float* pa_nm_g = (const float*)d_in[4];
  const float* pa_nm_b = (const float*)d_in[5];
  const float* pa_nl_g = (const float*)d_in[6];
  const float* pa_nl_b = (const float*)d_in[7];
  const float* Wq  = (const float*)d_in[8];
  const float* bq  = (const float*)d_in[9];
  const float* Wkv = (const float*)d_in[10];
  const float* bkv = (const float*)d_in[11];
  const float* Wo  = (const float*)d_in[12];
  const float* bo  = (const float*)d_in[13];
  const float* Wip = (const float*)d_in[14];
  const float* bip = (const float*)d_in[15];
  const float* Wop = (const float*)d_in[16];
  const float* bop = (const float*)d_in[17];
  const float* ln1_g = (const float*)d_in[18];
  const float* ln1_b = (const float*)d_in[19];
  const float* ln2_g = (const float*)d_in[20];
  const float* ln2_b = (const float*)d_in[21];
  const float* Wfc = (const float*)d_in[22];
  const float* bfc = (const float*)d_in[23];
  const float* Wpj = (const float*)d_in[24];
  const float* bpj = (const float*)d_in[25];
  float* out = (float*)d_out;

  char* p = (char*)d_ws;
  auto alloc = [&](size_t n)->char*{ char* r = p; p += (n + 255) & ~(size_t)255; return r; };
  u16* Wq_b  = (u16*)alloc((size_t)1024*512*2);
  u16* Wkv_b = (u16*)alloc((size_t)2048*512*2);
  u16* Wo_b  = (u16*)alloc((size_t)512*1024*2);
  u16* Wip_b = (u16*)alloc((size_t)1536*512*2);
  u16* Wop_b = (u16*)alloc((size_t)512*512*2);
  u16* Wfc_b = (u16*)alloc((size_t)2048*512*2);
  u16* Wpj_b = (u16*)alloc((size_t)512*2048*2);
  u16* l_b   = (u16*)alloc((size_t)128*512*2);
  u16* q_b   = (u16*)alloc((size_t)128*1024*2);
  u16* kvl_b = (u16*)alloc((size_t)128*2048*2);
  u16* xln_b = (u16*)alloc((size_t)32768*512*2);   // 33,554,432 B; dead after kvx GEMM
  u16* kvx_b = (u16*)alloc((size_t)32768*2048*2);
  u16* opa_b = (u16*)alloc((size_t)1024*1024*2);
  float* lat1 = (float*)alloc((size_t)1024*512*4);
  u16* y_b   = (u16*)alloc((size_t)1024*512*2);
  float* qkv2 = (float*)alloc((size_t)1024*1536*4);
  u16* o2_b  = (u16*)alloc((size_t)1024*512*2);
  float* lat2 = (float*)alloc((size_t)1024*512*4);
  u16* z_b   = (u16*)alloc((size_t)1024*512*2);
  u16* h1_b  = (u16*)alloc((size_t)1024*2048*2);
  float* m_part = (float*)alloc((size_t)8*64*128*4);
  float* l_part = (float*)alloc((size_t)8*64*128*4);
  // o_part [8 splits][64 bh][128 q][128 d] f32 = 33,554,432 B: aliases dead xln_b exactly.
  float* o_part = (float*)xln_b;

  {
    CvtArgs a;
    a.src[0]=Wq;  a.dst[0]=Wq_b;  a.n[0]=1024*512;
    a.src[1]=Wkv; a.dst[1]=Wkv_b; a.n[1]=2048*512;
    a.src[2]=Wo;  a.dst[2]=Wo_b;  a.n[2]=512*1024;
    a.src[3]=Wip; a.dst[3]=Wip_b; a.n[3]=1536*512;
    a.src[4]=Wop; a.dst[4]=Wop_b; a.n[4]=512*512;
    a.src[5]=Wfc; a.dst[5]=Wfc_b; a.n[5]=2048*512;
    a.src[6]=Wpj; a.dst[6]=Wpj_b; a.n[6]=512*2048;
    cvt_all_k<<<dim3(256, 7), 256, 0, stream>>>(a);
  }

  lat_ln2_k<<<128, 64, 0, stream>>>(latents, nl_g, nl_b, pa_nl_g, pa_nl_b, l_b);
  ln_rows_k<<<32768, 64, 0, stream>>>(visual, pa_nm_g, pa_nm_b, xln_b);

  // q = (l @ Wq^T + bq) * dh^-0.5   -> bf16 [128,1024]
  gemm64_k<1><<<dim3(16, 2), 256, 0, stream>>>(l_b, Wq_b, bq, nullptr, nullptr, q_b,
                                               128, 1024, 512, 0.08838834764831845f);
  // kv_l = l @ Wkv^T + bkv          -> bf16 [128,2048]
  gemm64_k<1><<<dim3(32, 2), 256, 0, stream>>>(l_b, Wkv_b, bkv, nullptr, nullptr, kvl_b,
                                               128, 2048, 512, 1.f);
  // kv_x = ln(visual) @ Wkv^T + bkv -> bf16 [32768,2048]  (must finish before o_part reuse)
  gemm_bt_k<1><<<dim3(16, 256), 256, 0, stream>>>(xln_b, Wkv_b, bkv, nullptr, nullptr, kvx_b,
                                                  32768, 2048, 512, 1.f);
  // flash attention, 8 KV-splits, then combine
  attn_pa_k<<<dim3(8, 8, 8), 512, 0, stream>>>(q_b, kvx_b, kvl_b, o_part, m_part, l_part);
  attn_comb_k<<<8192, 128, 0, stream>>>(o_part, m_part, l_part, opa_b);
  // lat1 = o @ Wo^T + bo -> f32 [1024,512]
  gemm64_k<0><<<dim3(8, 16), 256, 0, stream>>>(opa_b, Wo_b, bo, nullptr, lat1, nullptr,
                                               1024, 512, 1024, 1.f);
  ln_rows_k<<<1024, 64, 0, stream>>>(lat1, ln1_g, ln1_b, y_b);
  // qkv2 = y @ in_proj^T + b -> f32 [1024,1536]
  gemm64_k<0><<<dim3(24, 16), 256, 0, stream>>>(y_b, Wip_b, bip, nullptr, qkv2, nullptr,
                                                1024, 1536, 512, 1.f);
  attn2_k<<<dim3(128, 8), 64, 0, stream>>>(qkv2, o2_b);
  // lat2 = lat1 + o2 @ out_proj^T + b -> f32
  gemm64_k<4><<<dim3(8, 16), 256, 0, stream>>>(o2_b, Wop_b, bop, lat1, lat2, nullptr,
                                               1024, 512, 512, 1.f);
  ln_rows_k<<<1024, 64, 0, stream>>>(lat2, ln2_g, ln2_b, z_b);
  // h1 = qgelu(z @ Wfc^T + bfc) -> bf16 [1024,2048]
  gemm64_k<3><<<dim3(32, 16), 256, 0, stream>>>(z_b, Wfc_b, bfc, nullptr, nullptr, h1_b,
                                                1024, 2048, 512, 1.f);
  // out = lat2 + h1 @ Wproj^T + bproj -> f32 [1024,512]
  gemm64_k<4><<<dim3(8, 16), 256, 0, stream>>>(h1_b, Wpj_b, bpj, lat2, out, nullptr,
                                               1024, 512, 2048, 1.f);
}